// Round 2
// baseline (9238.536 us; speedup 1.0000x reference)
//
#include <hip/hip_runtime.h>

typedef _Float16 f16;
typedef f16   f16x8 __attribute__((ext_vector_type(8)));
typedef float f32x4 __attribute__((ext_vector_type(4)));
typedef unsigned short u16;

#define TSEQ 1024   // T
// B=128, N=M=256, 3M=768 fixed.

__device__ __forceinline__ float sigm(float x) {
    return __builtin_amdgcn_rcpf(1.0f + __expf(-x));
}
__device__ __forceinline__ float tanh_(float x) {
    return 1.0f - 2.0f * __builtin_amdgcn_rcpf(__expf(2.0f * x) + 1.0f);
}

// =====================================================================
// gx = A @ W^T + b_ih   (fp32 in, fp16 internal MFMA, fp16 out to ws)
// ws slice per (t,wgb): 12288 f16, LANE-MAJOR: off = w*1536 + gp*512 +
// lane*8 + (tau*4+i). (unchanged, verified)
// =====================================================================
__global__ __launch_bounds__(512, 2) void gemm_gx(
    const float* __restrict__ A, const float* __restrict__ W,
    const float* __restrict__ bih, f16* __restrict__ gx, int tc0, int TC)
{
    const int tid  = threadIdx.x;
    const int w    = tid >> 6;
    const int lane = tid & 63;
    const int c    = lane & 15;
    const int q    = lane >> 4;

    f16x8 wf[6][8];
    float bb[6];
#pragma unroll
    for (int k6 = 0; k6 < 6; ++k6) {
        const int g = (k6 >> 1) * 256 + w * 32 + (k6 & 1) * 16 + c;
        bb[k6] = bih[g];
#pragma unroll
        for (int kk = 0; kk < 8; ++kk) {
            const float* wp = W + g * 256 + kk * 32 + q * 8;
            f32x4 w0 = *(const f32x4*)wp, w1 = *(const f32x4*)(wp + 4);
            f16x8 v;
            v[0] = (f16)w0[0]; v[1] = (f16)w0[1]; v[2] = (f16)w0[2]; v[3] = (f16)w0[3];
            v[4] = (f16)w1[0]; v[5] = (f16)w1[1]; v[6] = (f16)w1[2]; v[7] = (f16)w1[3];
            wf[k6][kk] = v;
        }
    }

    const int ntiles = TC * 8;
    for (int tile = blockIdx.x; tile < ntiles; tile += gridDim.x) {
        const int tloc = tile >> 3, wgb = tile & 7;
        const int b0 = wgb * 16, t = tc0 + tloc;

        f32x4 acc[6];
#pragma unroll
        for (int k6 = 0; k6 < 6; ++k6) acc[k6] = (f32x4){0.f, 0.f, 0.f, 0.f};

        const float* Ab = A + ((long)(b0 + c) * TSEQ + t) * 256;   // A-frag row m=c
#pragma unroll
        for (int kk = 0; kk < 8; ++kk) {
            f32x4 a0 = *(const f32x4*)(Ab + kk * 32 + q * 8);
            f32x4 a1 = *(const f32x4*)(Ab + kk * 32 + q * 8 + 4);
            f16x8 a;
            a[0] = (f16)a0[0]; a[1] = (f16)a0[1]; a[2] = (f16)a0[2]; a[3] = (f16)a0[3];
            a[4] = (f16)a1[0]; a[5] = (f16)a1[1]; a[6] = (f16)a1[2]; a[7] = (f16)a1[3];
#pragma unroll
            for (int k6 = 0; k6 < 6; ++k6)
                acc[k6] = __builtin_amdgcn_mfma_f32_16x16x32_f16(a, wf[k6][kk], acc[k6], 0, 0, 0);
        }

        f16* gb = gx + (long)tile * 12288;
#pragma unroll
        for (int gp = 0; gp < 3; ++gp) {
            f16x8 v;
#pragma unroll
            for (int e = 0; e < 8; ++e) {
                const int tau = e >> 2, i = e & 3;
                v[e] = (f16)(acc[gp * 2 + tau][i] + bb[gp * 2 + tau]);
            }
            *(f16x8*)(gb + w * 1536 + gp * 512 + lane * 8) = v;
        }
    }
}

// =====================================================================
// GRU recurrence — round-0 verified structure (2x __syncthreads per step,
// gx double-buffered through LDS), with three LOCAL changes:
//  (1) hbuf rows are 512B with chunk ROTATION: phys_chunk = (logical +
//      4*row) & 31. For the MFMA A-frag read (fixed kk: 16 rows x 4
//      chunks) this spreads 64 lanes over all 32 banks at exactly 2
//      lanes/bank (free) instead of ~8-way conflicts.
//  (2) gx prefetch loads issued at TOP of step -> fully complete before
//      the vmcnt(0) drain at barrier 1.
//  (3) out[] stores for step t issued at START of phase 2 of step t+1
//      (fp32 values held in regs) -> gates phase covers the store drain
//      at barrier 2.
// =====================================================================
__global__ __launch_bounds__(512, 2) void gru_rec(
    const f16* __restrict__ gx, const float* __restrict__ Whh,
    const float* __restrict__ bhh, float* __restrict__ hcarry,
    float* __restrict__ out, float* __restrict__ hid,
    int tc0, int TC, int first, int last)
{
    __shared__ __align__(16) f16 gxb[2][12288];
    __shared__ __align__(16) f16 hbuf[16 * 256];   // [row=batch][32 chunks x 8 f16], rotated

    const int tid  = threadIdx.x;
    const int w    = tid >> 6;
    const int lane = tid & 63;
    const int c    = lane & 15;
    const int q    = lane >> 4;
    const int wgb  = blockIdx.x;
    const int b0   = wgb * 16;

    // w_hh -> fp16 fragments
    f16x8 wf[6][8];
#pragma unroll
    for (int k6 = 0; k6 < 6; ++k6) {
        const int g = (k6 >> 1) * 256 + w * 32 + (k6 & 1) * 16 + c;
#pragma unroll
        for (int kk = 0; kk < 8; ++kk) {
            const float* wp = Whh + g * 256 + kk * 32 + q * 8;
            f32x4 w0 = *(const f32x4*)wp, w1 = *(const f32x4*)(wp + 4);
            f16x8 v;
            v[0] = (f16)w0[0]; v[1] = (f16)w0[1]; v[2] = (f16)w0[2]; v[3] = (f16)w0[3];
            v[4] = (f16)w1[0]; v[5] = (f16)w1[1]; v[6] = (f16)w1[2]; v[7] = (f16)w1[3];
            wf[k6][kk] = v;
        }
    }

    // biases (f16-packed to save regs; |b|<0.3 so fp16 exact to 2^-12)
    f16 bhv[6];
#pragma unroll
    for (int tau = 0; tau < 2; ++tau) {
        const int j = w * 32 + tau * 16 + c;
        bhv[0 + tau] = (f16)bhh[j];
        bhv[2 + tau] = (f16)bhh[256 + j];
        bhv[4 + tau] = (f16)bhh[512 + j];
    }

    // h state: fp16 in regs (lane owns batch q*4+i, col j=w*32+tau*16+c)
    f16 hreg[8];
#pragma unroll
    for (int e = 0; e < 8; ++e) {
        const int tau = e >> 2, i = e & 3;
        const int b = q * 4 + i, j = w * 32 + tau * 16 + c;
        float hv = first ? 0.f : hcarry[(long)(b0 + b) * 256 + j];
        hreg[e] = (f16)hv;
        hbuf[b * 256 + ((((j >> 3) + 4 * b) & 31) << 3) + (j & 7)] = hreg[e];
    }

    // stage gx[tc0] into gxb[0]
    {
        const f16* sl = gx + (long)wgb * 12288;
#pragma unroll
        for (int gp = 0; gp < 3; ++gp) {
            f16x8 p = *(const f16x8*)(sl + w * 1536 + gp * 512 + lane * 8);
            *(f16x8*)(&gxb[0][w * 1536 + gp * 512 + lane * 8]) = p;
        }
    }
    __syncthreads();

    float houts[8];   // fp32 h of previous step, stored one step late

    int cur = 0;
    for (int tl = 0; tl < TC; ++tl) {
        const int t = tc0 + tl;

        // ---- prefetch gx[t+1] FIRST: whole MFMA phase covers the latency
        const int tln = (tl + 1 < TC) ? tl + 1 : tl;
        const f16* sl = gx + (long)(tln * 8 + wgb) * 12288;
        f16x8 p0 = *(const f16x8*)(sl + w * 1536 +        lane * 8);
        f16x8 p1 = *(const f16x8*)(sl + w * 1536 +  512 + lane * 8);
        f16x8 p2 = *(const f16x8*)(sl + w * 1536 + 1024 + lane * 8);

        // ---- phase 1: read gx + gh = h @ Whh^T (48 MFMA/wave) ----
        f16x8 gv0 = *(const f16x8*)(&gxb[cur][w * 1536 +          lane * 8]);
        f16x8 gv1 = *(const f16x8*)(&gxb[cur][w * 1536 +  512 +   lane * 8]);
        f16x8 gxn = *(const f16x8*)(&gxb[cur][w * 1536 + 1024 +   lane * 8]);

        f32x4 acc[6];
#pragma unroll
        for (int tau = 0; tau < 2; ++tau) {
#pragma unroll
            for (int i = 0; i < 4; ++i) {
                acc[tau][i]     = (float)gv0[tau * 4 + i] + (float)bhv[0 + tau];
                acc[2 + tau][i] = (float)gv1[tau * 4 + i] + (float)bhv[2 + tau];
                acc[4 + tau][i] = (float)bhv[4 + tau];
            }
        }
#pragma unroll
        for (int kk = 0; kk < 8; ++kk) {
            // rotated read: row c, phys chunk (4kk+q+4c)&31 -> 2 lanes/bank (free)
            f16x8 a = *(const f16x8*)(hbuf + c * 256 + (((4 * kk + q + 4 * c) & 31) << 3));
#pragma unroll
            for (int k6 = 0; k6 < 6; ++k6)
                acc[k6] = __builtin_amdgcn_mfma_f32_16x16x32_f16(a, wf[k6][kk], acc[k6], 0, 0, 0);
        }

        __syncthreads();   // all waves' h reads done; prefetch loads long complete

        // ---- deferred out[] stores of h(t-1): gates phase covers the drain
        if (tl > 0) {
#pragma unroll
            for (int e = 0; e < 8; ++e) {
                const int tau = e >> 2, i = e & 3;
                const int b = q * 4 + i, j = w * 32 + tau * 16 + c;
                out[((long)(b0 + b) * TSEQ + (t - 1)) * 256 + j] = houts[e];
            }
        }

        // ---- stage prefetch to other LDS buffer ----
        *(f16x8*)(&gxb[1 - cur][w * 1536 +        lane * 8]) = p0;
        *(f16x8*)(&gxb[1 - cur][w * 1536 +  512 + lane * 8]) = p1;
        *(f16x8*)(&gxb[1 - cur][w * 1536 + 1024 + lane * 8]) = p2;

        // ---- phase 2: gates + h update ----
#pragma unroll
        for (int tau = 0; tau < 2; ++tau) {
            const int j = w * 32 + tau * 16 + c;
#pragma unroll
            for (int i = 0; i < 4; ++i) {
                const int b = q * 4 + i;
                float r = sigm(acc[tau][i]);
                float z = sigm(acc[2 + tau][i]);
                float n = tanh_((float)gxn[tau * 4 + i] + r * acc[4 + tau][i]);
                float hp = (float)hreg[tau * 4 + i];
                float h = n + z * (hp - n);
                f16 hh = (f16)h;
                hreg[tau * 4 + i] = hh;
                hbuf[b * 256 + ((((j >> 3) + 4 * b) & 31) << 3) + (j & 7)] = hh;
                houts[tau * 4 + i] = h;
            }
        }
        __syncthreads();   // h(t+1) + gx stage visible
        cur ^= 1;
    }

    // final step's out stores
#pragma unroll
    for (int e = 0; e < 8; ++e) {
        const int tau = e >> 2, i = e & 3;
        const int b = q * 4 + i, j = w * 32 + tau * 16 + c;
        out[((long)(b0 + b) * TSEQ + (tc0 + TC - 1)) * 256 + j] = houts[e];
    }

    // persist h across chunks; final h_n if last chunk
#pragma unroll
    for (int e = 0; e < 8; ++e) {
        const int tau = e >> 2, i = e & 3;
        const long idx = (long)(b0 + q * 4 + i) * 256 + w * 32 + tau * 16 + c;
        hcarry[idx] = (float)hreg[e];
        if (last) hid[idx] = (float)hreg[e];
    }
}

// =====================================================================
extern "C" void kernel_launch(void* const* d_in, const int* in_sizes, int n_in,
                              void* d_out, int out_size, void* d_ws, size_t ws_size,
                              hipStream_t stream) {
    const float* X    = (const float*)d_in[0];
    const float* wih0 = (const float*)d_in[1];
    const float* whh0 = (const float*)d_in[2];
    const float* bih0 = (const float*)d_in[3];
    const float* bhh0 = (const float*)d_in[4];
    const float* wih1 = (const float*)d_in[5];
    const float* whh1 = (const float*)d_in[6];
    const float* bih1 = (const float*)d_in[7];
    const float* bhh1 = (const float*)d_in[8];

    float* out = (float*)d_out;                       // [128][1024][256] fp32
    float* hid = out + (long)128 * TSEQ * 256;        // [2][128][256] fp32

    // ws: [hcarry fp32 128x256 = 128KiB][gx f16 chunk: TC*8*12288*2 bytes]
    float* hcarry = (float*)d_ws;
    f16*   gxws   = (f16*)((char*)d_ws + 131072);

    int TC = TSEQ;
    while (TC > 16 && (size_t)131072 + (size_t)TC * 196608 > ws_size) TC >>= 1;

    const float* wih[2] = {wih0, wih1};
    const float* whh[2] = {whh0, whh1};
    const float* bih[2] = {bih0, bih1};
    const float* bhh[2] = {bhh0, bhh1};

    for (int layer = 0; layer < 2; ++layer) {
        const float* Ain = layer ? out : X;   // out0 staged in d_out region
        for (int tc0 = 0; tc0 < TSEQ; tc0 += TC) {
            const int ntiles = TC * 8;
            const int grid = ntiles < 512 ? ntiles : 512;
            gemm_gx<<<grid, 512, 0, stream>>>(Ain, wih[layer], bih[layer], gxws, tc0, TC);
            gru_rec<<<8, 512, 0, stream>>>(gxws, whh[layer], bhh[layer], hcarry,
                                           out, hid + (long)layer * 128 * 256,
                                           tc0, TC, tc0 == 0, tc0 + TC == TSEQ);
        }
    }
}

// Round 3
// 6111.588 us; speedup vs baseline: 1.5116x; 1.5116x over previous
//
#include <hip/hip_runtime.h>

typedef _Float16 f16;
typedef f16   f16x8 __attribute__((ext_vector_type(8)));
typedef float f32x4 __attribute__((ext_vector_type(4)));
typedef unsigned short u16;

#define TSEQ 1024   // T
// B=128, N=M=256, 3M=768 fixed.

__device__ __forceinline__ float sigm(float x) {
    return __builtin_amdgcn_rcpf(1.0f + __expf(-x));
}
__device__ __forceinline__ float tanh_(float x) {
    return 1.0f - 2.0f * __builtin_amdgcn_rcpf(__expf(2.0f * x) + 1.0f);
}

// LDS-only barrier: orders ds ops across waves WITHOUT draining vmcnt,
// so global prefetch loads and out[] stores float freely across it.
// (verified pattern: learn_hip m194-m201 8-phase template)
__device__ __forceinline__ void barrier_lds() {
    asm volatile("s_waitcnt lgkmcnt(0)" ::: "memory");
    __builtin_amdgcn_s_barrier();
    asm volatile("" ::: "memory");
}

// =====================================================================
// gx = A @ W^T + b_ih   (fp32 in, fp16 internal MFMA, fp16 out to ws)
// ws slice per (t,wgb): 12288 f16, LANE-MAJOR: off = w*1536 + gp*512 +
// lane*8 + (tau*4+i). (unchanged, verified)
// =====================================================================
__global__ __launch_bounds__(512, 2) void gemm_gx(
    const float* __restrict__ A, const float* __restrict__ W,
    const float* __restrict__ bih, f16* __restrict__ gx, int tc0, int TC)
{
    const int tid  = threadIdx.x;
    const int w    = tid >> 6;
    const int lane = tid & 63;
    const int c    = lane & 15;
    const int q    = lane >> 4;

    f16x8 wf[6][8];
    float bb[6];
#pragma unroll
    for (int k6 = 0; k6 < 6; ++k6) {
        const int g = (k6 >> 1) * 256 + w * 32 + (k6 & 1) * 16 + c;
        bb[k6] = bih[g];
#pragma unroll
        for (int kk = 0; kk < 8; ++kk) {
            const float* wp = W + g * 256 + kk * 32 + q * 8;
            f32x4 w0 = *(const f32x4*)wp, w1 = *(const f32x4*)(wp + 4);
            f16x8 v;
            v[0] = (f16)w0[0]; v[1] = (f16)w0[1]; v[2] = (f16)w0[2]; v[3] = (f16)w0[3];
            v[4] = (f16)w1[0]; v[5] = (f16)w1[1]; v[6] = (f16)w1[2]; v[7] = (f16)w1[3];
            wf[k6][kk] = v;
        }
    }

    const int ntiles = TC * 8;
    for (int tile = blockIdx.x; tile < ntiles; tile += gridDim.x) {
        const int tloc = tile >> 3, wgb = tile & 7;
        const int b0 = wgb * 16, t = tc0 + tloc;

        f32x4 acc[6];
#pragma unroll
        for (int k6 = 0; k6 < 6; ++k6) acc[k6] = (f32x4){0.f, 0.f, 0.f, 0.f};

        const float* Ab = A + ((long)(b0 + c) * TSEQ + t) * 256;   // A-frag row m=c
#pragma unroll
        for (int kk = 0; kk < 8; ++kk) {
            f32x4 a0 = *(const f32x4*)(Ab + kk * 32 + q * 8);
            f32x4 a1 = *(const f32x4*)(Ab + kk * 32 + q * 8 + 4);
            f16x8 a;
            a[0] = (f16)a0[0]; a[1] = (f16)a0[1]; a[2] = (f16)a0[2]; a[3] = (f16)a0[3];
            a[4] = (f16)a1[0]; a[5] = (f16)a1[1]; a[6] = (f16)a1[2]; a[7] = (f16)a1[3];
#pragma unroll
            for (int k6 = 0; k6 < 6; ++k6)
                acc[k6] = __builtin_amdgcn_mfma_f32_16x16x32_f16(a, wf[k6][kk], acc[k6], 0, 0, 0);
        }

        f16* gb = gx + (long)tile * 12288;
#pragma unroll
        for (int gp = 0; gp < 3; ++gp) {
            f16x8 v;
#pragma unroll
            for (int e = 0; e < 8; ++e) {
                const int tau = e >> 2, i = e & 3;
                v[e] = (f16)(acc[gp * 2 + tau][i] + bb[gp * 2 + tau]);
            }
            *(f16x8*)(gb + w * 1536 + gp * 512 + lane * 8) = v;
        }
    }
}

// =====================================================================
// GRU recurrence — round-0 verified structure (stride-264 hbuf: MFMA
// A-frag reads are conflict-free; 2 barriers/step; gx double-buffered
// via LDS; out stores inline in phase 2). Exactly two deltas vs round-0:
//  (1) gx prefetch issued at TOP of step (MFMA phase covers L3 latency)
//  (2) both barriers are raw lgkmcnt-only (no vmcnt(0) drain: neither
//      barrier orders any global-memory dependency)
// =====================================================================
__global__ __launch_bounds__(512, 2) void gru_rec(
    const f16* __restrict__ gx, const float* __restrict__ Whh,
    const float* __restrict__ bhh, float* __restrict__ hcarry,
    float* __restrict__ out, float* __restrict__ hid,
    int tc0, int TC, int first, int last)
{
    __shared__ __align__(16) f16 gxb[2][12288];
    __shared__ __align__(16) f16 hbuf[16 * 264];

    const int tid  = threadIdx.x;
    const int w    = tid >> 6;
    const int lane = tid & 63;
    const int c    = lane & 15;
    const int q    = lane >> 4;
    const int wgb  = blockIdx.x;
    const int b0   = wgb * 16;

    // w_hh -> fp16 fragments
    f16x8 wf[6][8];
#pragma unroll
    for (int k6 = 0; k6 < 6; ++k6) {
        const int g = (k6 >> 1) * 256 + w * 32 + (k6 & 1) * 16 + c;
#pragma unroll
        for (int kk = 0; kk < 8; ++kk) {
            const float* wp = Whh + g * 256 + kk * 32 + q * 8;
            f32x4 w0 = *(const f32x4*)wp, w1 = *(const f32x4*)(wp + 4);
            f16x8 v;
            v[0] = (f16)w0[0]; v[1] = (f16)w0[1]; v[2] = (f16)w0[2]; v[3] = (f16)w0[3];
            v[4] = (f16)w1[0]; v[5] = (f16)w1[1]; v[6] = (f16)w1[2]; v[7] = (f16)w1[3];
            wf[k6][kk] = v;
        }
    }

    // biases (f16-packed to save regs; |b|<0.3 so fp16 exact to 2^-12)
    f16 bhv[6];
#pragma unroll
    for (int tau = 0; tau < 2; ++tau) {
        const int j = w * 32 + tau * 16 + c;
        bhv[0 + tau] = (f16)bhh[j];
        bhv[2 + tau] = (f16)bhh[256 + j];
        bhv[4 + tau] = (f16)bhh[512 + j];
    }

    // h state: fp16 in regs (lane owns batch q*4+i, col j=w*32+tau*16+c)
    f16 hreg[8];
#pragma unroll
    for (int e = 0; e < 8; ++e) {
        const int tau = e >> 2, i = e & 3;
        float hv = first ? 0.f : hcarry[(long)(b0 + q * 4 + i) * 256 + w * 32 + tau * 16 + c];
        hreg[e] = (f16)hv;
        hbuf[(q * 4 + i) * 264 + w * 32 + tau * 16 + c] = hreg[e];
    }

    // stage gx[tc0] into gxb[0]
    {
        const f16* sl = gx + (long)wgb * 12288;
#pragma unroll
        for (int gp = 0; gp < 3; ++gp) {
            f16x8 p = *(const f16x8*)(sl + w * 1536 + gp * 512 + lane * 8);
            *(f16x8*)(&gxb[0][w * 1536 + gp * 512 + lane * 8]) = p;
        }
    }
    __syncthreads();   // prologue: full drain once

    int cur = 0;
    for (int tl = 0; tl < TC; ++tl) {
        const int t = tc0 + tl;

        // ---- prefetch gx[t+1] FIRST: MFMA phase covers the L3 latency ----
        const int tln = (tl + 1 < TC) ? tl + 1 : tl;
        const f16* sl = gx + (long)(tln * 8 + wgb) * 12288;
        f16x8 p0 = *(const f16x8*)(sl + w * 1536 +        lane * 8);
        f16x8 p1 = *(const f16x8*)(sl + w * 1536 +  512 + lane * 8);
        f16x8 p2 = *(const f16x8*)(sl + w * 1536 + 1024 + lane * 8);

        // ---- phase 1: read gx + gh = h @ Whh^T (48 MFMA/wave) ----
        f16x8 gv0 = *(const f16x8*)(&gxb[cur][w * 1536 +          lane * 8]);
        f16x8 gv1 = *(const f16x8*)(&gxb[cur][w * 1536 +  512 +   lane * 8]);
        f16x8 gxn = *(const f16x8*)(&gxb[cur][w * 1536 + 1024 +   lane * 8]);

        f32x4 acc[6];
#pragma unroll
        for (int tau = 0; tau < 2; ++tau) {
#pragma unroll
            for (int i = 0; i < 4; ++i) {
                acc[tau][i]     = (float)gv0[tau * 4 + i] + (float)bhv[0 + tau];
                acc[2 + tau][i] = (float)gv1[tau * 4 + i] + (float)bhv[2 + tau];
                acc[4 + tau][i] = (float)bhv[4 + tau];
            }
        }
#pragma unroll
        for (int kk = 0; kk < 8; ++kk) {
            f16x8 a = *(const f16x8*)(hbuf + c * 264 + kk * 32 + q * 8);
#pragma unroll
            for (int k6 = 0; k6 < 6; ++k6)
                acc[k6] = __builtin_amdgcn_mfma_f32_16x16x32_f16(a, wf[k6][kk], acc[k6], 0, 0, 0);
        }

        barrier_lds();     // all waves' h + gxb[cur] reads done (LDS only)

        // ---- stage prefetch to other LDS buffer ----
        *(f16x8*)(&gxb[1 - cur][w * 1536 +        lane * 8]) = p0;
        *(f16x8*)(&gxb[1 - cur][w * 1536 +  512 + lane * 8]) = p1;
        *(f16x8*)(&gxb[1 - cur][w * 1536 + 1024 + lane * 8]) = p2;

        // ---- phase 2: gates + h update ----
#pragma unroll
        for (int tau = 0; tau < 2; ++tau) {
            const int j = w * 32 + tau * 16 + c;
#pragma unroll
            for (int i = 0; i < 4; ++i) {
                const int b = q * 4 + i;
                float r = sigm(acc[tau][i]);
                float z = sigm(acc[2 + tau][i]);
                float n = tanh_((float)gxn[tau * 4 + i] + r * acc[4 + tau][i]);
                float hp = (float)hreg[tau * 4 + i];
                float h = n + z * (hp - n);
                f16 hh = (f16)h;
                hreg[tau * 4 + i] = hh;
                hbuf[b * 264 + j] = hh;
                out[((long)(b0 + b) * TSEQ + t) * 256 + j] = h;
            }
        }
        barrier_lds();     // h(t+1) + gx stage visible (LDS only)
        cur ^= 1;
    }

    // persist h across chunks; final h_n if last chunk
#pragma unroll
    for (int e = 0; e < 8; ++e) {
        const int tau = e >> 2, i = e & 3;
        const long idx = (long)(b0 + q * 4 + i) * 256 + w * 32 + tau * 16 + c;
        hcarry[idx] = (float)hreg[e];
        if (last) hid[idx] = (float)hreg[e];
    }
}

// =====================================================================
extern "C" void kernel_launch(void* const* d_in, const int* in_sizes, int n_in,
                              void* d_out, int out_size, void* d_ws, size_t ws_size,
                              hipStream_t stream) {
    const float* X    = (const float*)d_in[0];
    const float* wih0 = (const float*)d_in[1];
    const float* whh0 = (const float*)d_in[2];
    const float* bih0 = (const float*)d_in[3];
    const float* bhh0 = (const float*)d_in[4];
    const float* wih1 = (const float*)d_in[5];
    const float* whh1 = (const float*)d_in[6];
    const float* bih1 = (const float*)d_in[7];
    const float* bhh1 = (const float*)d_in[8];

    float* out = (float*)d_out;                       // [128][1024][256] fp32
    float* hid = out + (long)128 * TSEQ * 256;        // [2][128][256] fp32

    // ws: [hcarry fp32 128x256 = 128KiB][gx f16 chunk: TC*8*12288*2 bytes]
    float* hcarry = (float*)d_ws;
    f16*   gxws   = (f16*)((char*)d_ws + 131072);

    int TC = TSEQ;
    while (TC > 16 && (size_t)131072 + (size_t)TC * 196608 > ws_size) TC >>= 1;

    const float* wih[2] = {wih0, wih1};
    const float* whh[2] = {whh0, whh1};
    const float* bih[2] = {bih0, bih1};
    const float* bhh[2] = {bhh0, bhh1};

    for (int layer = 0; layer < 2; ++layer) {
        const float* Ain = layer ? out : X;   // out0 staged in d_out region
        for (int tc0 = 0; tc0 < TSEQ; tc0 += TC) {
            const int ntiles = TC * 8;
            const int grid = ntiles < 512 ? ntiles : 512;
            gemm_gx<<<grid, 512, 0, stream>>>(Ain, wih[layer], bih[layer], gxws, tc0, TC);
            gru_rec<<<8, 512, 0, stream>>>(gxws, whh[layer], bhh[layer], hcarry,
                                           out, hid + (long)layer * 128 * 256,
                                           tc0, TC, tc0 == 0, tc0 + TC == TSEQ);
        }
    }
}

// Round 4
// 4855.975 us; speedup vs baseline: 1.9025x; 1.2586x over previous
//
#include <hip/hip_runtime.h>

typedef _Float16 f16;
typedef f16   f16x8 __attribute__((ext_vector_type(8)));
typedef float f32x4 __attribute__((ext_vector_type(4)));

#define TSEQ 1024   // T
// B=128, N=M=256, 3M=768 fixed.

__device__ __forceinline__ float sigm(float x) {
    return __builtin_amdgcn_rcpf(1.0f + __expf(-x));
}
__device__ __forceinline__ float tanh_(float x) {
    return 1.0f - 2.0f * __builtin_amdgcn_rcpf(__expf(2.0f * x) + 1.0f);
}

// LDS-only barrier: orders ds ops across waves WITHOUT draining vmcnt.
__device__ __forceinline__ void barrier_lds() {
    asm volatile("s_waitcnt lgkmcnt(0)" ::: "memory");
    __builtin_amdgcn_s_barrier();
    asm volatile("" ::: "memory");
}

// =====================================================================
// gx = A @ W^T + (b_ih [+ b_hh for r,z])   (fp32 in, fp16 MFMA, f16 out)
// ws slice per (t,wgb): 12288 f16, LANE-MAJOR: off = w*1536 + gp*512 +
// lane*8 + (tau*4+i). b_hh folded for gp<2 (r,z); n keeps b_hh separate
// (it is scaled by r inside the recurrence).
// =====================================================================
__global__ __launch_bounds__(512, 2) void gemm_gx(
    const float* __restrict__ A, const float* __restrict__ W,
    const float* __restrict__ bih, const float* __restrict__ bhh,
    f16* __restrict__ gx, int tc0, int TC)
{
    const int tid  = threadIdx.x;
    const int w    = tid >> 6;
    const int lane = tid & 63;
    const int c    = lane & 15;
    const int q    = lane >> 4;

    f16x8 wf[6][8];
    float bb[6];
#pragma unroll
    for (int k6 = 0; k6 < 6; ++k6) {
        const int g = (k6 >> 1) * 256 + w * 32 + (k6 & 1) * 16 + c;
        bb[k6] = bih[g] + (k6 < 4 ? bhh[g] : 0.f);   // fold b_hh into r,z
#pragma unroll
        for (int kk = 0; kk < 8; ++kk) {
            const float* wp = W + g * 256 + kk * 32 + q * 8;
            f32x4 w0 = *(const f32x4*)wp, w1 = *(const f32x4*)(wp + 4);
            f16x8 v;
            v[0] = (f16)w0[0]; v[1] = (f16)w0[1]; v[2] = (f16)w0[2]; v[3] = (f16)w0[3];
            v[4] = (f16)w1[0]; v[5] = (f16)w1[1]; v[6] = (f16)w1[2]; v[7] = (f16)w1[3];
            wf[k6][kk] = v;
        }
    }

    const int ntiles = TC * 8;
    for (int tile = blockIdx.x; tile < ntiles; tile += gridDim.x) {
        const int tloc = tile >> 3, wgb = tile & 7;
        const int b0 = wgb * 16, t = tc0 + tloc;

        f32x4 acc[6];
#pragma unroll
        for (int k6 = 0; k6 < 6; ++k6) acc[k6] = (f32x4){0.f, 0.f, 0.f, 0.f};

        const float* Ab = A + ((long)(b0 + c) * TSEQ + t) * 256;   // A-frag row m=c
#pragma unroll
        for (int kk = 0; kk < 8; ++kk) {
            f32x4 a0 = *(const f32x4*)(Ab + kk * 32 + q * 8);
            f32x4 a1 = *(const f32x4*)(Ab + kk * 32 + q * 8 + 4);
            f16x8 a;
            a[0] = (f16)a0[0]; a[1] = (f16)a0[1]; a[2] = (f16)a0[2]; a[3] = (f16)a0[3];
            a[4] = (f16)a1[0]; a[5] = (f16)a1[1]; a[6] = (f16)a1[2]; a[7] = (f16)a1[3];
#pragma unroll
            for (int k6 = 0; k6 < 6; ++k6)
                acc[k6] = __builtin_amdgcn_mfma_f32_16x16x32_f16(a, wf[k6][kk], acc[k6], 0, 0, 0);
        }

        f16* gb = gx + (long)tile * 12288;
#pragma unroll
        for (int gp = 0; gp < 3; ++gp) {
            f16x8 v;
#pragma unroll
            for (int e = 0; e < 8; ++e) {
                const int tau = e >> 2, i = e & 3;
                v[e] = (f16)(acc[gp * 2 + tau][i] + bb[gp * 2 + tau]);
            }
            *(f16x8*)(gb + w * 1536 + gp * 512 + lane * 8) = v;
        }
    }
}

// =====================================================================
// GRU recurrence — same 2-barrier sync skeleton as the verified round-0
// kernel, restructured inside each step for MFMA||VALU overlap:
//  - gx kept in REGISTERS (lane-private; no LDS round trip, no gxb)
//  - chain-major MFMA: even chains (k6=0,2,4 -> tau=0 cols) first, then
//    odd chains (k6=1,3,5) with tau=0 gate elements INTERLEAVED between
//    MFMAs (dependency-free -> scheduler co-issues trans/VALU under the
//    MFMA pipe). tau=1 gates after. A-frags re-read in the odd loop to
//    keep VGPR/wave <= 256 (both waves stay resident per SIMD).
//  - barrier 1: all waves' h(t) reads done -> h(t+1) scatter writes
//  - barrier 2: h(t+1) visible
// =====================================================================
__global__ __launch_bounds__(512, 2) void gru_rec(
    const f16* __restrict__ gx, const float* __restrict__ Whh,
    const float* __restrict__ bhh, float* __restrict__ hcarry,
    float* __restrict__ out, float* __restrict__ hid,
    int tc0, int TC, int first, int last)
{
    __shared__ __align__(16) f16 hbuf[16 * 264];   // stride-264: conflict-free A-frag reads

    const int tid  = threadIdx.x;
    const int w    = tid >> 6;
    const int lane = tid & 63;
    const int c    = lane & 15;
    const int q    = lane >> 4;
    const int wgb  = blockIdx.x;
    const int b0   = wgb * 16;

    // w_hh -> fp16 fragments (lives mostly in AGPRs, gfx950 unified file)
    f16x8 wf[6][8];
#pragma unroll
    for (int k6 = 0; k6 < 6; ++k6) {
        const int g = (k6 >> 1) * 256 + w * 32 + (k6 & 1) * 16 + c;
#pragma unroll
        for (int kk = 0; kk < 8; ++kk) {
            const float* wp = Whh + g * 256 + kk * 32 + q * 8;
            f32x4 w0 = *(const f32x4*)wp, w1 = *(const f32x4*)(wp + 4);
            f16x8 v;
            v[0] = (f16)w0[0]; v[1] = (f16)w0[1]; v[2] = (f16)w0[2]; v[3] = (f16)w0[3];
            v[4] = (f16)w1[0]; v[5] = (f16)w1[1]; v[6] = (f16)w1[2]; v[7] = (f16)w1[3];
            wf[k6][kk] = v;
        }
    }

    // only b_hh_n needed here (r,z folded into gx by gemm_gx)
    float bbn[2];
#pragma unroll
    for (int tau = 0; tau < 2; ++tau)
        bbn[tau] = bhh[512 + w * 32 + tau * 16 + c];

    // h state: fp16 in regs (lane owns batch q*4+i, col j=w*32+tau*16+c)
    f16 hreg[8];
#pragma unroll
    for (int e = 0; e < 8; ++e) {
        const int tau = e >> 2, i = e & 3;
        float hv = first ? 0.f : hcarry[(long)(b0 + q * 4 + i) * 256 + w * 32 + tau * 16 + c];
        hreg[e] = (f16)hv;
        hbuf[(q * 4 + i) * 264 + w * 32 + tau * 16 + c] = hreg[e];
    }

    // gx addressing: slice(t) = gx + (t*8+wgb)*12288 ; within: w*1536+gp*512+lane*8
    const f16* gbase = gx + (long)wgb * 12288 + (long)w * 1536 + lane * 8;

    // gx(t=tc0) -> registers
    f16x8 g0 = *(const f16x8*)(gbase);
    f16x8 g1 = *(const f16x8*)(gbase + 512);
    f16x8 g2 = *(const f16x8*)(gbase + 1024);

    __syncthreads();   // prologue: full drain once

    for (int tl = 0; tl < TC; ++tl) {
        const int t = tc0 + tl;

        // ---- prefetch gx(t+1) into regs: whole step covers the latency ----
        const int tln = (tl + 1 < TC) ? tl + 1 : tl;
        const f16* sl = gbase + (long)tln * (8 * 12288);
        f16x8 p0 = *(const f16x8*)(sl);
        f16x8 p1 = *(const f16x8*)(sl + 512);
        f16x8 p2 = *(const f16x8*)(sl + 1024);

        // ---- acc init: gx regs (r,z biases pre-folded) + b_hh_n ----
        f32x4 acc[6];
#pragma unroll
        for (int tau = 0; tau < 2; ++tau) {
#pragma unroll
            for (int i = 0; i < 4; ++i) {
                acc[tau][i]     = (float)g0[tau * 4 + i];
                acc[2 + tau][i] = (float)g1[tau * 4 + i];
                acc[4 + tau][i] = bbn[tau];
            }
        }

        // ---- even chains: k6 = 0,2,4 (r,z,n for tau=0 columns) ----
#pragma unroll
        for (int kk = 0; kk < 8; ++kk) {
            f16x8 a = *(const f16x8*)(hbuf + c * 264 + kk * 32 + q * 8);
            acc[0] = __builtin_amdgcn_mfma_f32_16x16x32_f16(a, wf[0][kk], acc[0], 0, 0, 0);
            acc[2] = __builtin_amdgcn_mfma_f32_16x16x32_f16(a, wf[2][kk], acc[2], 0, 0, 0);
            acc[4] = __builtin_amdgcn_mfma_f32_16x16x32_f16(a, wf[4][kk], acc[4], 0, 0, 0);
        }

        // ---- odd chains (k6 = 1,3,5) with tau=0 gates interleaved ----
#pragma unroll
        for (int kk = 0; kk < 8; ++kk) {
            f16x8 a = *(const f16x8*)(hbuf + c * 264 + kk * 32 + q * 8);
            acc[1] = __builtin_amdgcn_mfma_f32_16x16x32_f16(a, wf[1][kk], acc[1], 0, 0, 0);
            acc[3] = __builtin_amdgcn_mfma_f32_16x16x32_f16(a, wf[3][kk], acc[3], 0, 0, 0);
            acc[5] = __builtin_amdgcn_mfma_f32_16x16x32_f16(a, wf[5][kk], acc[5], 0, 0, 0);
            if (kk < 4) {   // gate element i=kk of tau=0: deps only on acc[0],[2],[4]
                const int i = kk;
                const int j = w * 32 + c;
                const int b = q * 4 + i;
                float r = sigm(acc[0][i]);
                float z = sigm(acc[2][i]);
                float n = tanh_((float)g2[i] + r * acc[4][i]);
                float hp = (float)hreg[i];
                float h = n + z * (hp - n);
                hreg[i] = (f16)h;
                out[((long)(b0 + b) * TSEQ + t) * 256 + j] = h;
            }
        }

        // ---- tau=1 gates ----
#pragma unroll
        for (int i = 0; i < 4; ++i) {
            const int j = w * 32 + 16 + c;
            const int b = q * 4 + i;
            float r = sigm(acc[1][i]);
            float z = sigm(acc[3][i]);
            float n = tanh_((float)g2[4 + i] + r * acc[5][i]);
            float hp = (float)hreg[4 + i];
            float h = n + z * (hp - n);
            hreg[4 + i] = (f16)h;
            out[((long)(b0 + b) * TSEQ + t) * 256 + j] = h;
        }

        // rotate gx regs
        g0 = p0; g1 = p1; g2 = p2;

        barrier_lds();     // all waves' h(t) reads done (LDS only)

        // ---- h(t+1) scatter to hbuf ----
#pragma unroll
        for (int e = 0; e < 8; ++e) {
            const int tau = e >> 2, i = e & 3;
            hbuf[(q * 4 + i) * 264 + w * 32 + tau * 16 + c] = hreg[e];
        }

        barrier_lds();     // h(t+1) visible (LDS only)
    }

    // persist h across chunks; final h_n if last chunk
#pragma unroll
    for (int e = 0; e < 8; ++e) {
        const int tau = e >> 2, i = e & 3;
        const long idx = (long)(b0 + q * 4 + i) * 256 + w * 32 + tau * 16 + c;
        hcarry[idx] = (float)hreg[e];
        if (last) hid[idx] = (float)hreg[e];
    }
}

// =====================================================================
extern "C" void kernel_launch(void* const* d_in, const int* in_sizes, int n_in,
                              void* d_out, int out_size, void* d_ws, size_t ws_size,
                              hipStream_t stream) {
    const float* X    = (const float*)d_in[0];
    const float* wih0 = (const float*)d_in[1];
    const float* whh0 = (const float*)d_in[2];
    const float* bih0 = (const float*)d_in[3];
    const float* bhh0 = (const float*)d_in[4];
    const float* wih1 = (const float*)d_in[5];
    const float* whh1 = (const float*)d_in[6];
    const float* bih1 = (const float*)d_in[7];
    const float* bhh1 = (const float*)d_in[8];

    float* out = (float*)d_out;                       // [128][1024][256] fp32
    float* hid = out + (long)128 * TSEQ * 256;        // [2][128][256] fp32

    // ws: [hcarry fp32 128x256 = 128KiB][gx f16 chunk: TC*8*12288*2 bytes]
    float* hcarry = (float*)d_ws;
    f16*   gxws   = (f16*)((char*)d_ws + 131072);

    int TC = TSEQ;
    while (TC > 16 && (size_t)131072 + (size_t)TC * 196608 > ws_size) TC >>= 1;

    const float* wih[2] = {wih0, wih1};
    const float* whh[2] = {whh0, whh1};
    const float* bih[2] = {bih0, bih1};
    const float* bhh[2] = {bhh0, bhh1};

    for (int layer = 0; layer < 2; ++layer) {
        const float* Ain = layer ? out : X;   // out0 staged in d_out region
        for (int tc0 = 0; tc0 < TSEQ; tc0 += TC) {
            const int ntiles = TC * 8;
            const int grid = ntiles < 512 ? ntiles : 512;
            gemm_gx<<<grid, 512, 0, stream>>>(Ain, wih[layer], bih[layer], bhh[layer],
                                              gxws, tc0, TC);
            gru_rec<<<8, 512, 0, stream>>>(gxws, whh[layer], bhh[layer], hcarry,
                                           out, hid + (long)layer * 128 * 256,
                                           tc0, TC, tc0 == 0, tc0 + TC == TSEQ);
        }
    }
}

// Round 5
// 4427.051 us; speedup vs baseline: 2.0868x; 1.0969x over previous
//
#include <hip/hip_runtime.h>

typedef _Float16 f16;
typedef f16   f16x8 __attribute__((ext_vector_type(8)));
typedef f16   f16x4 __attribute__((ext_vector_type(4)));
typedef float f32x4 __attribute__((ext_vector_type(4)));

#define TSEQ 1024   // T
// B=128, N=M=256, 3M=768 fixed.

__device__ __forceinline__ float sigm(float x) {
    return __builtin_amdgcn_rcpf(1.0f + __expf(-x));
}
__device__ __forceinline__ float tanh_(float x) {
    return 1.0f - 2.0f * __builtin_amdgcn_rcpf(__expf(2.0f * x) + 1.0f);
}

// LDS-only barrier: orders ds ops across waves WITHOUT draining vmcnt.
__device__ __forceinline__ void barrier_lds() {
    asm volatile("s_waitcnt lgkmcnt(0)" ::: "memory");
    __builtin_amdgcn_s_barrier();
    asm volatile("" ::: "memory");
}

// =====================================================================
// gx = A @ W^T + (b_ih [+ b_hh for r,z])   — UNCHANGED from round 4.
// ws slice per (t,wgb16): 12288 f16: value(gate gp, col j, batch b16) at
// (j>>5)*1536 + gp*512 + ((b16>>2)*16 + (j&15))*8 + ((j>>4)&1)*4 + (b16&3)
// =====================================================================
__global__ __launch_bounds__(512, 2) void gemm_gx(
    const float* __restrict__ A, const float* __restrict__ W,
    const float* __restrict__ bih, const float* __restrict__ bhh,
    f16* __restrict__ gx, int tc0, int TC)
{
    const int tid  = threadIdx.x;
    const int w    = tid >> 6;
    const int lane = tid & 63;
    const int c    = lane & 15;
    const int q    = lane >> 4;

    f16x8 wf[6][8];
    float bb[6];
#pragma unroll
    for (int k6 = 0; k6 < 6; ++k6) {
        const int g = (k6 >> 1) * 256 + w * 32 + (k6 & 1) * 16 + c;
        bb[k6] = bih[g] + (k6 < 4 ? bhh[g] : 0.f);   // fold b_hh into r,z
#pragma unroll
        for (int kk = 0; kk < 8; ++kk) {
            const float* wp = W + g * 256 + kk * 32 + q * 8;
            f32x4 w0 = *(const f32x4*)wp, w1 = *(const f32x4*)(wp + 4);
            f16x8 v;
            v[0] = (f16)w0[0]; v[1] = (f16)w0[1]; v[2] = (f16)w0[2]; v[3] = (f16)w0[3];
            v[4] = (f16)w1[0]; v[5] = (f16)w1[1]; v[6] = (f16)w1[2]; v[7] = (f16)w1[3];
            wf[k6][kk] = v;
        }
    }

    const int ntiles = TC * 8;
    for (int tile = blockIdx.x; tile < ntiles; tile += gridDim.x) {
        const int tloc = tile >> 3, wgb = tile & 7;
        const int b0 = wgb * 16, t = tc0 + tloc;

        f32x4 acc[6];
#pragma unroll
        for (int k6 = 0; k6 < 6; ++k6) acc[k6] = (f32x4){0.f, 0.f, 0.f, 0.f};

        const float* Ab = A + ((long)(b0 + c) * TSEQ + t) * 256;   // A-frag row m=c
#pragma unroll
        for (int kk = 0; kk < 8; ++kk) {
            f32x4 a0 = *(const f32x4*)(Ab + kk * 32 + q * 8);
            f32x4 a1 = *(const f32x4*)(Ab + kk * 32 + q * 8 + 4);
            f16x8 a;
            a[0] = (f16)a0[0]; a[1] = (f16)a0[1]; a[2] = (f16)a0[2]; a[3] = (f16)a0[3];
            a[4] = (f16)a1[0]; a[5] = (f16)a1[1]; a[6] = (f16)a1[2]; a[7] = (f16)a1[3];
#pragma unroll
            for (int k6 = 0; k6 < 6; ++k6)
                acc[k6] = __builtin_amdgcn_mfma_f32_16x16x32_f16(a, wf[k6][kk], acc[k6], 0, 0, 0);
        }

        f16* gb = gx + (long)tile * 12288;
#pragma unroll
        for (int gp = 0; gp < 3; ++gp) {
            f16x8 v;
#pragma unroll
            for (int e = 0; e < 8; ++e) {
                const int tau = e >> 2, i = e & 3;
                v[e] = (f16)(acc[gp * 2 + tau][i] + bb[gp * 2 + tau]);
            }
            *(f16x8*)(gb + w * 1536 + gp * 512 + lane * 8) = v;
        }
    }
}

// =====================================================================
// GRU recurrence — 16 WGs x 8 batches (2x CUs) with LDS gate
// redistribution. Per step:
//   phase A (producer): 48 MFMA/wave over hbuf rows 0-7 (rows 8-15
//     zeroed; D rows 8-15 garbage, discarded). Lanes q<2 dump the 24
//     valid gate pre-activations per chain-set to accb (f32, [3][256][12]
//     pad -> throughput-floor bank patterns).
//   barrier 1 (lgkm-only)
//   phase B (consumer): thread tid -> (col j=tid>>1, half=tid&1, 4
//     batches). Reads r/z/n b128 from accb + gx (b64 global, coalesced,
//     prefetched 1 step ahead), 4x gate math (trans-bound, HALVED
//     per-thread vs nb=16), writes h to hbuf rows 0-7 + out.
//   barrier 2 (lgkm-only)
// Gate VALU per SIMD halves; MFMA (30% busy) absorbs the 2x tile waste.
// =====================================================================
__global__ __launch_bounds__(512, 2) void gru_rec(
    const f16* __restrict__ gx, const float* __restrict__ Whh,
    const float* __restrict__ bhh, float* __restrict__ hcarry,
    float* __restrict__ out, float* __restrict__ hid,
    int tc0, int TC, int first, int last)
{
    __shared__ __align__(16) float accb[3 * 256 * 12];   // 36 KB, [gate][col][batch pad 12]
    __shared__ __align__(16) f16 hbuf[16 * 264];         // rows 0-7 live, 8-15 zero

    const int tid  = threadIdx.x;
    const int w    = tid >> 6;
    const int lane = tid & 63;
    const int c    = lane & 15;
    const int q    = lane >> 4;
    const int wgb8 = blockIdx.x;        // 0..15, 8 batches each
    const int bg   = wgb8 * 8;

    // consumer role: col j, batch half-block
    const int j    = tid >> 1;
    const int half = tid & 1;

    // w_hh -> fp16 fragments
    f16x8 wf[6][8];
#pragma unroll
    for (int k6 = 0; k6 < 6; ++k6) {
        const int g = (k6 >> 1) * 256 + w * 32 + (k6 & 1) * 16 + c;
#pragma unroll
        for (int kk = 0; kk < 8; ++kk) {
            const float* wp = Whh + g * 256 + kk * 32 + q * 8;
            f32x4 w0 = *(const f32x4*)wp, w1 = *(const f32x4*)(wp + 4);
            f16x8 v;
            v[0] = (f16)w0[0]; v[1] = (f16)w0[1]; v[2] = (f16)w0[2]; v[3] = (f16)w0[3];
            v[4] = (f16)w1[0]; v[5] = (f16)w1[1]; v[6] = (f16)w1[2]; v[7] = (f16)w1[3];
            wf[k6][kk] = v;
        }
    }

    const float bbn = bhh[512 + j];     // b_hh_n for consumer's column

    // zero hbuf (incl. rows 8-15 read by MFMA as zeros)
    for (int k = tid; k < 16 * 264; k += 512) hbuf[k] = (f16)0.f;
    __syncthreads();

    // h state in consumer mapping: thread owns (j, batches half*4+i)
    f16 hreg[4];
#pragma unroll
    for (int i = 0; i < 4; ++i) {
        float hv = first ? 0.f : hcarry[(long)(bg + half * 4 + i) * 256 + j];
        hreg[i] = (f16)hv;
        hbuf[(half * 4 + i) * 264 + j] = hreg[i];
    }

    // gx consumer address (f16 units within a 12288-slice, old gemm layout):
    const int q16   = (wgb8 & 1) * 2 + half;
    const int gxoff = (j >> 5) * 1536 + (q16 * 16 + (j & 15)) * 8 + ((j >> 4) & 1) * 4;
    const int wgb16 = wgb8 >> 1;

    f16x4 gr, gz, gn;
    {
        const f16* sl = gx + (long)wgb16 * 12288 + gxoff;
        gr = *(const f16x4*)(sl);
        gz = *(const f16x4*)(sl + 512);
        gn = *(const f16x4*)(sl + 1024);
    }
    __syncthreads();   // prologue: full drain once

    for (int tl = 0; tl < TC; ++tl) {
        const int t = tc0 + tl;

        // ---- prefetch gx(t+1): whole step covers the latency ----
        const int tln = (tl + 1 < TC) ? tl + 1 : tl;
        const f16* sl = gx + ((long)tln * 8 + wgb16) * 12288 + gxoff;
        f16x4 p0 = *(const f16x4*)(sl);
        f16x4 p1 = *(const f16x4*)(sl + 512);
        f16x4 p2 = *(const f16x4*)(sl + 1024);

        // ---- phase A: gh = h @ Whh^T (48 MFMA/wave, C-init 0) ----
        f32x4 acc[6];
#pragma unroll
        for (int k6 = 0; k6 < 6; ++k6) acc[k6] = (f32x4){0.f, 0.f, 0.f, 0.f};
#pragma unroll
        for (int kk = 0; kk < 8; ++kk) {
            f16x8 a = *(const f16x8*)(hbuf + c * 264 + kk * 32 + q * 8);
#pragma unroll
            for (int k6 = 0; k6 < 6; ++k6)
                acc[k6] = __builtin_amdgcn_mfma_f32_16x16x32_f16(a, wf[k6][kk], acc[k6], 0, 0, 0);
        }

        // ---- dump valid gate pre-activations (D rows 0-7 <=> q<2) ----
        if (q < 2) {
#pragma unroll
            for (int k6 = 0; k6 < 6; ++k6) {
                const int gp = k6 >> 1;
                const int jj = w * 32 + (k6 & 1) * 16 + c;
                *(f32x4*)(&accb[(gp * 256 + jj) * 12 + q * 4]) = acc[k6];
            }
        }

        barrier_lds();     // accb visible; all hbuf reads done

        // ---- phase B: redistributed gates (4 h-elements/thread) ----
        f32x4 ar = *(const f32x4*)(&accb[(0 * 256 + j) * 12 + half * 4]);
        f32x4 az = *(const f32x4*)(&accb[(1 * 256 + j) * 12 + half * 4]);
        f32x4 an = *(const f32x4*)(&accb[(2 * 256 + j) * 12 + half * 4]);
#pragma unroll
        for (int i = 0; i < 4; ++i) {
            float r = sigm((float)gr[i] + ar[i]);
            float z = sigm((float)gz[i] + az[i]);
            float n = tanh_((float)gn[i] + r * (an[i] + bbn));
            float hp = (float)hreg[i];
            float h = n + z * (hp - n);
            hreg[i] = (f16)h;
            hbuf[(half * 4 + i) * 264 + j] = hreg[i];
            out[((long)(bg + half * 4 + i) * TSEQ + t) * 256 + j] = h;
        }
        gr = p0; gz = p1; gn = p2;

        barrier_lds();     // h(t+1) visible; accb consumed (WAR for next A)
    }

    // persist h across chunks; final h_n if last chunk
#pragma unroll
    for (int i = 0; i < 4; ++i) {
        const long idx = (long)(bg + half * 4 + i) * 256 + j;
        hcarry[idx] = (float)hreg[i];
        if (last) hid[idx] = (float)hreg[i];
    }
}

// =====================================================================
extern "C" void kernel_launch(void* const* d_in, const int* in_sizes, int n_in,
                              void* d_out, int out_size, void* d_ws, size_t ws_size,
                              hipStream_t stream) {
    const float* X    = (const float*)d_in[0];
    const float* wih0 = (const float*)d_in[1];
    const float* whh0 = (const float*)d_in[2];
    const float* bih0 = (const float*)d_in[3];
    const float* bhh0 = (const float*)d_in[4];
    const float* wih1 = (const float*)d_in[5];
    const float* whh1 = (const float*)d_in[6];
    const float* bih1 = (const float*)d_in[7];
    const float* bhh1 = (const float*)d_in[8];

    float* out = (float*)d_out;                       // [128][1024][256] fp32
    float* hid = out + (long)128 * TSEQ * 256;        // [2][128][256] fp32

    // ws: [hcarry fp32 128x256 = 128KiB][gx f16 chunk: TC*8*12288*2 bytes]
    float* hcarry = (float*)d_ws;
    f16*   gxws   = (f16*)((char*)d_ws + 131072);

    int TC = TSEQ;
    while (TC > 16 && (size_t)131072 + (size_t)TC * 196608 > ws_size) TC >>= 1;

    const float* wih[2] = {wih0, wih1};
    const float* whh[2] = {whh0, whh1};
    const float* bih[2] = {bih0, bih1};
    const float* bhh[2] = {bhh0, bhh1};

    for (int layer = 0; layer < 2; ++layer) {
        const float* Ain = layer ? out : X;   // out0 staged in d_out region
        for (int tc0 = 0; tc0 < TSEQ; tc0 += TC) {
            const int ntiles = TC * 8;
            const int grid = ntiles < 512 ? ntiles : 512;
            gemm_gx<<<grid, 512, 0, stream>>>(Ain, wih[layer], bih[layer], bhh[layer],
                                              gxws, tc0, TC);
            gru_rec<<<16, 512, 0, stream>>>(gxws, whh[layer], bhh[layer], hcarry,
                                            out, hid + (long)layer * 128 * 256,
                                            tc0, TC, tc0 == 0, tc0 + TC == TSEQ);
        }
    }
}

// Round 6
// 3691.314 us; speedup vs baseline: 2.5028x; 1.1993x over previous
//
#include <hip/hip_runtime.h>

typedef _Float16 f16;
typedef f16   f16x8 __attribute__((ext_vector_type(8)));
typedef f16   f16x4 __attribute__((ext_vector_type(4)));
typedef float f32x4 __attribute__((ext_vector_type(4)));

#define TSEQ 1024   // T
// B=128, N=M=256, 3M=768 fixed.

__device__ __forceinline__ float sigm(float x) {
    return __builtin_amdgcn_rcpf(1.0f + __expf(-x));
}
__device__ __forceinline__ float tanh_(float x) {
    return 1.0f - 2.0f * __builtin_amdgcn_rcpf(__expf(2.0f * x) + 1.0f);
}

// LDS-only barrier: orders ds ops across waves WITHOUT draining vmcnt.
__device__ __forceinline__ void barrier_lds() {
    asm volatile("s_waitcnt lgkmcnt(0)" ::: "memory");
    __builtin_amdgcn_s_barrier();
    asm volatile("" ::: "memory");
}

// =====================================================================
// gemm role: gx = A @ W^T + (b_ih [+ b_hh for r,z]), grid-strided over
// this chunk's TC*8 tiles by nblk blocks. Body identical to the verified
// round-5 gemm_gx, with parameterized block index.
// =====================================================================
__device__ void gemm_role(const float* __restrict__ A, const float* __restrict__ W,
                          const float* __restrict__ bih, const float* __restrict__ bhh,
                          f16* __restrict__ gxslot, int tc0, int TC, int idx, int nblk)
{
    const int tid  = threadIdx.x;
    const int w    = tid >> 6;
    const int lane = tid & 63;
    const int c    = lane & 15;
    const int q    = lane >> 4;

    f16x8 wf[6][8];
    float bb[6];
#pragma unroll
    for (int k6 = 0; k6 < 6; ++k6) {
        const int g = (k6 >> 1) * 256 + w * 32 + (k6 & 1) * 16 + c;
        bb[k6] = bih[g] + (k6 < 4 ? bhh[g] : 0.f);   // fold b_hh into r,z
#pragma unroll
        for (int kk = 0; kk < 8; ++kk) {
            const float* wp = W + g * 256 + kk * 32 + q * 8;
            f32x4 w0 = *(const f32x4*)wp, w1 = *(const f32x4*)(wp + 4);
            f16x8 v;
            v[0] = (f16)w0[0]; v[1] = (f16)w0[1]; v[2] = (f16)w0[2]; v[3] = (f16)w0[3];
            v[4] = (f16)w1[0]; v[5] = (f16)w1[1]; v[6] = (f16)w1[2]; v[7] = (f16)w1[3];
            wf[k6][kk] = v;
        }
    }

    const int ntiles = TC * 8;
    for (int tile = idx; tile < ntiles; tile += nblk) {
        const int tloc = tile >> 3, wgb = tile & 7;
        const int b0 = wgb * 16, t = tc0 + tloc;

        f32x4 acc[6];
#pragma unroll
        for (int k6 = 0; k6 < 6; ++k6) acc[k6] = (f32x4){0.f, 0.f, 0.f, 0.f};

        const float* Ab = A + ((long)(b0 + c) * TSEQ + t) * 256;   // A-frag row m=c
#pragma unroll
        for (int kk = 0; kk < 8; ++kk) {
            f32x4 a0 = *(const f32x4*)(Ab + kk * 32 + q * 8);
            f32x4 a1 = *(const f32x4*)(Ab + kk * 32 + q * 8 + 4);
            f16x8 a;
            a[0] = (f16)a0[0]; a[1] = (f16)a0[1]; a[2] = (f16)a0[2]; a[3] = (f16)a0[3];
            a[4] = (f16)a1[0]; a[5] = (f16)a1[1]; a[6] = (f16)a1[2]; a[7] = (f16)a1[3];
#pragma unroll
            for (int k6 = 0; k6 < 6; ++k6)
                acc[k6] = __builtin_amdgcn_mfma_f32_16x16x32_f16(a, wf[k6][kk], acc[k6], 0, 0, 0);
        }

        f16* gb = gxslot + (long)tile * 12288;
#pragma unroll
        for (int gp = 0; gp < 3; ++gp) {
            f16x8 v;
#pragma unroll
            for (int e = 0; e < 8; ++e) {
                const int tau = e >> 2, i = e & 3;
                v[e] = (f16)(acc[gp * 2 + tau][i] + bb[gp * 2 + tau]);
            }
            *(f16x8*)(gb + w * 1536 + gp * 512 + lane * 8) = v;
        }
    }
}

// =====================================================================
// rec role: round-5 verified recurrence (16 WGs x 8 batches, LDS gate
// redistribution), with accb re-laid-out DENSE [3][256][8] f32:
//   phase-B reads are tid-sequential 16B (conflict-free);
//   phase-A dumps land 2 lanes/4-bank-group (free).
// =====================================================================
__device__ void rec_role(const f16* __restrict__ gx, const float* __restrict__ Whh,
                         const float* __restrict__ bhh, float* __restrict__ hcarry,
                         float* out, float* __restrict__ hid,
                         int tc0, int TC, int first, int last, int wgb8,
                         float* accb, f16* hbuf)
{
    const int tid  = threadIdx.x;
    const int w    = tid >> 6;
    const int lane = tid & 63;
    const int c    = lane & 15;
    const int q    = lane >> 4;
    const int bg   = wgb8 * 8;
    const int j    = tid >> 1;       // consumer: gate/output column
    const int half = tid & 1;        // consumer: batch half-block

    // w_hh -> fp16 fragments
    f16x8 wf[6][8];
#pragma unroll
    for (int k6 = 0; k6 < 6; ++k6) {
        const int g = (k6 >> 1) * 256 + w * 32 + (k6 & 1) * 16 + c;
#pragma unroll
        for (int kk = 0; kk < 8; ++kk) {
            const float* wp = Whh + g * 256 + kk * 32 + q * 8;
            f32x4 w0 = *(const f32x4*)wp, w1 = *(const f32x4*)(wp + 4);
            f16x8 v;
            v[0] = (f16)w0[0]; v[1] = (f16)w0[1]; v[2] = (f16)w0[2]; v[3] = (f16)w0[3];
            v[4] = (f16)w1[0]; v[5] = (f16)w1[1]; v[6] = (f16)w1[2]; v[7] = (f16)w1[3];
            wf[k6][kk] = v;
        }
    }

    const float bbn = bhh[512 + j];     // b_hh_n for consumer's column

    // zero hbuf (incl. rows 8-15 read by MFMA as zeros)
    for (int k = tid; k < 16 * 264; k += 512) hbuf[k] = (f16)0.f;
    __syncthreads();

    // h state in consumer mapping
    f16 hreg[4];
#pragma unroll
    for (int i = 0; i < 4; ++i) {
        float hv = first ? 0.f : hcarry[(long)(bg + half * 4 + i) * 256 + j];
        hreg[i] = (f16)hv;
        hbuf[(half * 4 + i) * 264 + j] = hreg[i];
    }

    // gx consumer address (f16 units within a 12288-slice, gemm layout)
    const int q16   = (wgb8 & 1) * 2 + half;
    const int gxoff = (j >> 5) * 1536 + (q16 * 16 + (j & 15)) * 8 + ((j >> 4) & 1) * 4;
    const int wgb16 = wgb8 >> 1;

    f16x4 gr, gz, gn;
    {
        const f16* sl = gx + (long)wgb16 * 12288 + gxoff;
        gr = *(const f16x4*)(sl);
        gz = *(const f16x4*)(sl + 512);
        gn = *(const f16x4*)(sl + 1024);
    }
    __syncthreads();   // prologue: full drain once

    for (int tl = 0; tl < TC; ++tl) {
        const int t = tc0 + tl;

        // ---- prefetch gx(t+1): whole step covers the latency ----
        const int tln = (tl + 1 < TC) ? tl + 1 : tl;
        const f16* sl = gx + ((long)tln * 8 + wgb16) * 12288 + gxoff;
        f16x4 p0 = *(const f16x4*)(sl);
        f16x4 p1 = *(const f16x4*)(sl + 512);
        f16x4 p2 = *(const f16x4*)(sl + 1024);

        // ---- phase A: gh = h @ Whh^T (48 MFMA/wave, C-init 0) ----
        f32x4 acc[6];
#pragma unroll
        for (int k6 = 0; k6 < 6; ++k6) acc[k6] = (f32x4){0.f, 0.f, 0.f, 0.f};
#pragma unroll
        for (int kk = 0; kk < 8; ++kk) {
            f16x8 a = *(const f16x8*)(hbuf + c * 264 + kk * 32 + q * 8);
#pragma unroll
            for (int k6 = 0; k6 < 6; ++k6)
                acc[k6] = __builtin_amdgcn_mfma_f32_16x16x32_f16(a, wf[k6][kk], acc[k6], 0, 0, 0);
        }

        // ---- dump valid gate pre-activations (rows 0-7 <=> q<2), dense ----
        if (q < 2) {
#pragma unroll
            for (int k6 = 0; k6 < 6; ++k6) {
                const int gp = k6 >> 1;
                const int jj = w * 32 + (k6 & 1) * 16 + c;
                *(f32x4*)(&accb[(gp * 256 + jj) * 8 + q * 4]) = acc[k6];
            }
        }

        barrier_lds();     // accb visible; all hbuf reads done

        // ---- phase B: redistributed gates (4 h-elements/thread) ----
        f32x4 ar = *(const f32x4*)(&accb[(0 * 256 + j) * 8 + half * 4]);
        f32x4 az = *(const f32x4*)(&accb[(1 * 256 + j) * 8 + half * 4]);
        f32x4 an = *(const f32x4*)(&accb[(2 * 256 + j) * 8 + half * 4]);
#pragma unroll
        for (int i = 0; i < 4; ++i) {
            float r = sigm((float)gr[i] + ar[i]);
            float z = sigm((float)gz[i] + az[i]);
            float n = tanh_((float)gn[i] + r * (an[i] + bbn));
            float hp = (float)hreg[i];
            float h = n + z * (hp - n);
            hreg[i] = (f16)h;
            hbuf[(half * 4 + i) * 264 + j] = hreg[i];
            out[((long)(bg + half * 4 + i) * TSEQ + t) * 256 + j] = h;
        }
        gr = p0; gz = p1; gn = p2;

        barrier_lds();     // h(t+1) visible; accb consumed
    }

    // persist h across chunks; final h_n if last chunk
#pragma unroll
    for (int i = 0; i < 4; ++i) {
        const long idx = (long)(bg + half * 4 + i) * 256 + j;
        hcarry[idx] = (float)hreg[i];
        if (last) hid[idx] = (float)hreg[i];
    }
}

// =====================================================================
// Fused pipelined launch F(c). All four groups are data-independent
// WITHIN a launch; every dependency crosses a launch boundary (stream
// order provides it):
//   blocks   0- 15 : rec  layer0 chunk c      (needs gemm0(c): F(c-1))
//   blocks  16- 31 : rec  layer1 chunk c-2    (needs gemm1(c-2): F(c-1))
//   blocks  32-143 : gemm layer0 chunk c+1    (input X, no rec dep)
//   blocks 144-255 : gemm layer1 chunk c-1    (needs rec0(c-1): F(c-1))
// gx rings: layer L slot (chunk&1) -> producer/consumer always disjoint.
// out chunks: rec0 writes c, gemm1 reads c-1, rec1 overwrites c-2.
// LDS padded to 82176 B (>80 KiB) -> hardware pins 1 block/CU, so the
// 32 rec blocks never share a CU with gemm blocks. (128-KiB static LDS
// precedent: gemm_256sq_8phase example.)
// =====================================================================
__global__ __launch_bounds__(512, 2) void fused(
    const float* __restrict__ X,
    const float* __restrict__ wih0, const float* __restrict__ whh0,
    const float* __restrict__ bih0, const float* __restrict__ bhh0,
    const float* __restrict__ wih1, const float* __restrict__ whh1,
    const float* __restrict__ bih1, const float* __restrict__ bhh1,
    f16* gx0, f16* gx1, float* hc0, float* hc1,
    float* out, float* hid, int c, int TC, int C)
{
    // 18432 f32 = 73728 B (only first 6144 used) + 8448 B = 82176 B total:
    // the oversizing is the 1-block/CU pin.
    __shared__ __align__(16) float accb[18432];
    __shared__ __align__(16) f16  hbuf[16 * 264];

    const long SLOT = (long)TC * 98304;   // f16 elems per gx ring slot
    const int bid = blockIdx.x;

    if (bid < 16) {                       // rec layer 0, chunk c
        if (c >= 0 && c < C)
            rec_role(gx0 + (long)(c & 1) * SLOT, whh0, bhh0, hc0,
                     out, hid, c * TC, TC, c == 0, c == C - 1, bid, accb, hbuf);
    } else if (bid < 32) {                // rec layer 1, chunk c-2
        const int k = c - 2;
        if (k >= 0 && k < C)
            rec_role(gx1 + (long)(k & 1) * SLOT, whh1, bhh1, hc1,
                     out, hid + (long)128 * 256, k * TC, TC, k == 0, k == C - 1,
                     bid - 16, accb, hbuf);
    } else if (bid < 144) {               // gemm layer 0, chunk c+1
        const int k = c + 1;
        if (k >= 0 && k < C)
            gemm_role(X, wih0, bih0, bhh0, gx0 + (long)(k & 1) * SLOT,
                      k * TC, TC, bid - 32, 112);
    } else {                              // gemm layer 1, chunk c-1
        const int k = c - 1;
        if (k >= 0 && k < C)
            gemm_role(out, wih1, bih1, bhh1, gx1 + (long)(k & 1) * SLOT,
                      k * TC, TC, bid - 144, 112);
    }
}

// =====================================================================
extern "C" void kernel_launch(void* const* d_in, const int* in_sizes, int n_in,
                              void* d_out, int out_size, void* d_ws, size_t ws_size,
                              hipStream_t stream) {
    const float* X    = (const float*)d_in[0];
    const float* wih0 = (const float*)d_in[1];
    const float* whh0 = (const float*)d_in[2];
    const float* bih0 = (const float*)d_in[3];
    const float* bhh0 = (const float*)d_in[4];
    const float* wih1 = (const float*)d_in[5];
    const float* whh1 = (const float*)d_in[6];
    const float* bih1 = (const float*)d_in[7];
    const float* bhh1 = (const float*)d_in[8];

    float* out = (float*)d_out;                       // [128][1024][256] fp32
    float* hid = out + (long)128 * TSEQ * 256;        // [2][128][256] fp32

    // ws: [hc0 128KiB][hc1 128KiB][gx0 ring: 2 slots][gx1 ring: 2 slots]
    // slot = TC*8*12288 f16 = TC*196608 B
    int TC = 64;
    while (TC > 4 && (size_t)262144 + (size_t)4 * TC * 196608 > ws_size) TC >>= 1;
    const int C = TSEQ / TC;

    float* hc0 = (float*)d_ws;
    float* hc1 = hc0 + 32768;
    f16*   gx0 = (f16*)((char*)d_ws + 262144);
    f16*   gx1 = gx0 + (long)2 * TC * 98304;

    for (int c = -1; c <= C + 1; ++c)
        fused<<<256, 512, 0, stream>>>(X, wih0, whh0, bih0, bhh0,
                                       wih1, whh1, bih1, bhh1,
                                       gx0, gx1, hc0, hc1, out, hid, c, TC, C);
}